// Round 5
// baseline (614.602 us; speedup 1.0000x reference)
//
#include <hip/hip_runtime.h>
#include <hip/hip_fp16.h>

// ---------------------------------------------------------------------------
// 3-layer GCN, 2 dispatches (R17): tiny memset + ONE persistent mega-kernel.
// Phases inside the mega-kernel, separated by manual device-scope grid
// barriers (GRID=768 blocks, __launch_bounds__(256,4) -> >=4 blocks/CU
// resident => 768 co-resident guaranteed; barrier is deadlock-free by
// construction, no dependence on dispatch order):
//  P1: [phase1 bucket-sort chunks (LDS-staged -> coalesced arena writes)]
//      + [gemm1 h1 = x0 @ W1] as grid-stride units
//  P2: phase2 per-bucket node sort -> row_ptr/cnt/dinv + u16 eidx; layer-0
//      buckets prescale h1 in place; counting-sort nodes by degree -> perm
//  P3: gather1 (plain adds over prescaled h1') + gemm2 -> h2'
//  P4: gather2 (plain adds over prescaled h2') + gemm3 -> h3'
//  P5: gather3 (plain adds over prescaled h3') -> out
// Rationale (R17): R15/R16 internal optimizations were flat; compulsory work
// is ~40-60us but window is 160us -> testing the per-dispatch/inter-dispatch
// overhead theory by collapsing 6 dispatches to 2.
// NOTE (R6): f32 LDS atomicAdd is a serializing slow path on gfx950.
// NOTE (R12): hipLaunchCooperativeKernel fails silently under graph capture
//   -> manual atomic grid barrier instead (agent-scope acq/rel).
// NOTE (R13): phase1 LDS-staged scatter -> coalesced arena writes. -9us.
// NOTE (R14): prescaled h* removes per-edge dinv broadcasts. -5us.
// NOTE (R15/R16): divergence sort / barrier reduction: flat -> kernels are
//   not issue- or barrier-bound at this scale.
// ---------------------------------------------------------------------------

#define NB   256            // buckets per layer (W = ceil(n/NB) = 196 < 512)
#define NL   3
#define TB   (NB * NL)      // 768 buckets
#define CAPE 6400           // arena capacity per bucket (mean fill ~3125)
#define CAPE_E (CAPE + 8)   // u16 eidx arena stride (+8 spill room)
#define CH   2048           // edges per phase-1 chunk
#define PT   256            // threads per block (all phases)
#define EPT  (CH / PT)      // 8
#define GRID 768            // co-resident by __launch_bounds__(256,4)

__device__ __forceinline__ void decode_chunk(int g, int nc1, int nc2,
                                             const int* s1, const int* d1, int E1,
                                             const int* s2, const int* d2, int E2,
                                             const int* s3, const int* d3, int E3,
                                             const int** src, const int** dst, int* E, int* l,
                                             int* gout) {
    if (g < nc1)            { *src = s1; *dst = d1; *E = E1; *l = 0; }
    else if (g < nc1 + nc2) { *src = s2; *dst = d2; *E = E2; *l = 1; g -= nc1; }
    else                    { *src = s3; *dst = d3; *E = E3; *l = 2; g -= nc1 + nc2; }
    *gout = g;
}

__device__ __forceinline__ void fma4(float4& a, float s, const float4& w) {
    a.x += s * w.x; a.y += s * w.y; a.z += s * w.z; a.w += s * w.w;
}
__device__ __forceinline__ void add4(float4& a, const float4& v) {
    a.x += v.x; a.y += v.y; a.z += v.z; a.w += v.w;
}
__device__ __forceinline__ float4 ldh4(const __half* h, size_t idx4) {
    uint2 r = ((const uint2*)h)[idx4];
    __half2 a = *reinterpret_cast<__half2*>(&r.x);
    __half2 b = *reinterpret_cast<__half2*>(&r.y);
    float2 fa = __half22float2(a), fb = __half22float2(b);
    return make_float4(fa.x, fa.y, fb.x, fb.y);
}
__device__ __forceinline__ void sth4(__half* h, size_t idx4, float4 v) {
    __half2 a = __floats2half2_rn(v.x, v.y);
    __half2 b = __floats2half2_rn(v.z, v.w);
    uint2 r;
    r.x = *reinterpret_cast<unsigned*>(&a);
    r.y = *reinterpret_cast<unsigned*>(&b);
    ((uint2*)h)[idx4] = r;
}

// Inclusive wave scan (wave64) of v.
__device__ __forceinline__ int wave_incl_scan(int v) {
    int incl = v;
#pragma unroll
    for (int off = 1; off < 64; off <<= 1) {
        int u = __shfl_up(incl, (unsigned)off, 64);
        if ((threadIdx.x & 63) >= off) incl += u;
    }
    return incl;
}

// Device-scope grid barrier: all GRID blocks are co-resident (launch bounds),
// so spin is deadlock-free. Fresh counter per phase (no sense reversal).
__device__ __forceinline__ void gbar(int* bar, int idx) {
    __syncthreads();
    if (threadIdx.x == 0) {
        __threadfence();   // release prior writes
        __hip_atomic_fetch_add(&bar[idx], 1, __ATOMIC_ACQ_REL, __HIP_MEMORY_SCOPE_AGENT);
        while (__hip_atomic_load(&bar[idx], __ATOMIC_RELAXED, __HIP_MEMORY_SCOPE_AGENT) < GRID)
            __builtin_amdgcn_s_sleep(1);
        __threadfence();   // acquire others' writes
    }
    __syncthreads();
}

__global__ void __launch_bounds__(PT, 4) mega(
        const int* __restrict__ s1, const int* __restrict__ d1, int E1,
        const int* __restrict__ s2, const int* __restrict__ d2, int E2,
        const int* __restrict__ s3, const int* __restrict__ d3, int E3,
        int nc1, int nc2, int W, int nchunks, int gemmBlks, int n,
        int* __restrict__ gcur, int* __restrict__ bar,
        unsigned int* __restrict__ pairBuf, unsigned short* __restrict__ eidx,
        int* __restrict__ row_ptr, int* __restrict__ cnt_g,
        float* __restrict__ dinv, int* __restrict__ perm,
        const float* __restrict__ x0, const float* __restrict__ W1g,
        const float* __restrict__ b1, const float* __restrict__ W2g,
        const float* __restrict__ b2, const float* __restrict__ W3g,
        const float* __restrict__ b3,
        __half* __restrict__ h1, __half* __restrict__ h2, __half* __restrict__ h3,
        float* __restrict__ out) {
    __shared__ __align__(16) char smem[17408];
    __shared__ int wsum[4];
    const int t = threadIdx.x;
    const int bid = blockIdx.x;
    const int lane = t & 63, wid = t >> 6;

    // ---------------- Phase 1: edge bucket-sort + gemm1 ----------------
    for (int u = bid; u < nchunks + gemmBlks; u += GRID) {
        if (u < nchunks) {
            int* hist = (int*)smem;                       // 256
            int* eofs = hist + NB;                        // 256
            int* bo   = eofs + NB;                        // 256
            int* lcur = bo + NB;                          // 256
            unsigned* stage = (unsigned*)(smem + 4096);   // 8KB (CH u32)
            unsigned char* stageQ = (unsigned char*)(smem + 12288); // 2KB
            hist[t] = 0;
            __syncthreads();
            const int* src; const int* dst; int E, l, g;
            decode_chunk(u, nc1, nc2, s1, d1, E1, s2, d2, E2, s3, d3, E3,
                         &src, &dst, &E, &l, &g);
            const int e0 = g * CH;
            const int lbase = l * NB;
            unsigned pv[EPT];
            int bn[EPT];
            if (E - e0 >= CH) {
                const int4* s4 = (const int4*)(src + e0);
                const int4* d4 = (const int4*)(dst + e0);
#pragma unroll
                for (int w = 0; w < EPT / 4; ++w) {
                    int4 sv = s4[t + w * PT];
                    int4 dv = d4[t + w * PT];
                    int q, i = w * 4;
                    q = dv.x / W; bn[i+0] = q; pv[i+0] = ((unsigned)sv.x << 9) | (unsigned)(dv.x - q * W);
                    q = dv.y / W; bn[i+1] = q; pv[i+1] = ((unsigned)sv.y << 9) | (unsigned)(dv.y - q * W);
                    q = dv.z / W; bn[i+2] = q; pv[i+2] = ((unsigned)sv.z << 9) | (unsigned)(dv.z - q * W);
                    q = dv.w / W; bn[i+3] = q; pv[i+3] = ((unsigned)sv.w << 9) | (unsigned)(dv.w - q * W);
                }
            } else {
#pragma unroll
                for (int i = 0; i < EPT; ++i) {
                    int e = e0 + t + i * PT;
                    if (e < E) {
                        int s = src[e], d = dst[e];
                        int q = d / W;
                        bn[i] = q;
                        pv[i] = ((unsigned)s << 9) | (unsigned)(d - q * W);
                    } else bn[i] = -1;
                }
            }
#pragma unroll
            for (int i = 0; i < EPT; ++i)
                if (bn[i] >= 0) atomicAdd(&hist[bn[i]], 1);
            __syncthreads();
            // Wave-shuffle exclusive scan over NB=256 counts (4 waves).
            const int c = hist[t];
            int incl = wave_incl_scan(c);
            if (lane == 63) wsum[wid] = incl;
            __syncthreads();
            int base = 0, total = 0;
#pragma unroll
            for (int w = 0; w < 4; ++w) {
                int s = wsum[w];
                total += s;
                if (w < wid) base += s;
            }
            const int excl = base + incl - c;
            eofs[t] = excl;
            lcur[t] = excl;
            bo[t] = (lbase + t) * CAPE + (c ? atomicAdd(&gcur[lbase + t], c) : 0);
            __syncthreads();
#pragma unroll
            for (int i = 0; i < EPT; ++i) {
                if (bn[i] >= 0) {
                    int r = atomicAdd(&lcur[bn[i]], 1);
                    stage[r] = pv[i];
                    stageQ[r] = (unsigned char)bn[i];
                }
            }
            __syncthreads();
            for (int i = t; i < total; i += PT) {
                int q = stageQ[i];
                int k = bo[q] + (i - eofs[q]);
                if (k < (lbase + q + 1) * CAPE) pairBuf[k] = stage[i];
            }
        } else {
            float* Ws = (float*)smem;               // 16 KB
            const int gb = u - nchunks;
            for (int i = t; i < 1024; i += PT)
                ((float4*)Ws)[i] = ((const float4*)W1g)[i];
            __syncthreads();
            const int tc = t % 16;
            const int tr = t / 16;                  // 64 rows/unit
            const int row0 = gb * 64 + tr * 4;
            const float4* x4 = (const float4*)x0;
            const float4* Ws4 = (const float4*)Ws;
            float4 acc[4];
#pragma unroll
            for (int r = 0; r < 4; ++r) acc[r] = make_float4(0.f, 0.f, 0.f, 0.f);
            int rowc[4];
#pragma unroll
            for (int r = 0; r < 4; ++r) rowc[r] = min(row0 + r, n - 1);
            for (int k0 = 0; k0 < 64; k0 += 4) {
                float4 wv0 = Ws4[(k0 + 0) * 16 + tc];
                float4 wv1 = Ws4[(k0 + 1) * 16 + tc];
                float4 wv2 = Ws4[(k0 + 2) * 16 + tc];
                float4 wv3 = Ws4[(k0 + 3) * 16 + tc];
#pragma unroll
                for (int r = 0; r < 4; ++r) {
                    float4 xv = x4[(size_t)rowc[r] * 16 + (k0 / 4)];
                    fma4(acc[r], xv.x, wv0);
                    fma4(acc[r], xv.y, wv1);
                    fma4(acc[r], xv.z, wv2);
                    fma4(acc[r], xv.w, wv3);
                }
            }
#pragma unroll
            for (int r = 0; r < 4; ++r) {
                int row = row0 + r;
                if (row < n) sth4(h1, (size_t)row * 16 + tc, acc[r]);
            }
        }
        __syncthreads();
    }
    gbar(bar, 0);

    // ---------------- Phase 2: per-bucket node sort + prescale + perm ----
    for (int u = bid; u < TB; u += GRID) {
        int* lcnt  = (int*)smem;                               // 1KB
        int* lscan = (int*)(smem + 1024);                      // 1KB
        unsigned short* stage = (unsigned short*)(smem + 2048);// 12.8KB
        float* dloc = (float*)(smem + 14848);                  // 1KB
        const int l = u / NB, k2 = u % NB;
        const int lo = k2 * W;
        const int hi = min(n, lo + W);
        const int Wn = hi - lo;
        const int segE = min(gcur[u], CAPE);
        const size_t base  = (size_t)u * CAPE;
        const int    baseE = u * CAPE_E;
        lcnt[t] = 0;
        __syncthreads();
        for (int i = t; i < segE; i += PT)
            atomicAdd(&lcnt[pairBuf[base + i] & 511u], 1);
        __syncthreads();
        const int v = lcnt[t];
        const int vp = (v + 3) & ~3;
        int incl = wave_incl_scan(vp);
        if (lane == 63) wsum[wid] = incl;
        __syncthreads();
        int sbase = 0, segEp = 0;
#pragma unroll
        for (int w = 0; w < 4; ++w) {
            int s = wsum[w];
            segEp += s;
            if (w < wid) sbase += s;
        }
        const int pexcl = sbase + incl - vp;
        if (t < Wn) {
            int node = l * n + lo + t;
            row_ptr[node] = baseE + pexcl;
            cnt_g[node] = v;
            float dv = rsqrtf((float)v + 1.0f);   // +1 self-loop
            dinv[node] = dv;
            dloc[t] = dv;
        }
        __syncthreads();
        lcnt[t] = pexcl;
        __syncthreads();
        const bool lds_ok = (segEp <= CAPE);
        for (int i = t; i < segE; i += PT) {
            unsigned p = pairBuf[base + i];
            int pos = atomicAdd(&lcnt[p & 511u], 1);
            unsigned short s = (unsigned short)(p >> 9);
            if (lds_ok) stage[pos] = s;
            else if (pos < CAPE_E) eidx[baseE + pos] = s;
        }
        __syncthreads();
        if (lds_ok) {
            const int4* st4 = (const int4*)stage;
            int4* e4 = (int4*)(eidx + baseE);
            int m16 = (segEp + 7) >> 3;
            for (int i = t; i < m16; i += PT) e4[i] = st4[i];
        }
        // Layer-0 buckets prescale their h1 rows: h1' = dinv1 * h1raw.
        if (l == 0) {
            for (int i = t; i < Wn * 16; i += PT) {
                int r = i >> 4, cc = i & 15;
                size_t idx = (size_t)(lo + r) * 16 + cc;
                float4 vv = ldh4(h1, idx);
                float s = dloc[r];
                vv.x *= s; vv.y *= s; vv.z *= s; vv.w *= s;
                sth4(h1, idx, vv);
            }
        }
        // Counting-sort nodes by degree -> perm.
        __syncthreads();
        lcnt[t] = 0;
        __syncthreads();
        int key = 0, myr = 0;
        if (t < Wn) {
            key = min(v, 255);
            myr = atomicAdd(&lcnt[key], 1);
        }
        __syncthreads();
        const int c2 = lcnt[t];
        int incl2 = wave_incl_scan(c2);
        if (lane == 63) wsum[wid] = incl2;
        __syncthreads();
        int base2 = 0;
#pragma unroll
        for (int w = 0; w < 4; ++w)
            if (w < wid) base2 += wsum[w];
        lscan[t] = base2 + incl2 - c2;
        __syncthreads();
        if (t < Wn) perm[l * n + lo + lscan[key] + myr] = lo + t;
        __syncthreads();
    }
    gbar(bar, 1);

    // ---------------- Phase 3: gather1 + gemm2 ----------------
    {
        float* W2s = (float*)smem;                  // 8 KB
        float* xs  = (float*)(smem + 8192);         // 16*68 f32
        for (int i = t; i < 512; i += PT)
            ((float4*)W2s)[i] = ((const float4*)W2g)[i];
        __syncthreads();
        const int ln = t >> 4;
        const int f4 = t & 15;
        const int nu = (n + 15) / 16;
        for (int u = bid; u < nu; u += GRID) {
            const int gidx = u * 16 + ln;
            const int node = (gidx < n) ? perm[gidx] : 0;
            if (gidx < n) {
                const int beg = row_ptr[node];
                const int m = cnt_g[node];
                float4 a0 = make_float4(0.f, 0.f, 0.f, 0.f), a1 = a0, a2 = a0, a3 = a0;
                int j = 0;
                for (; j + 8 <= m; j += 8) {
                    ushort4 e0 = *(const ushort4*)(eidx + beg + j);
                    ushort4 e1 = *(const ushort4*)(eidx + beg + j + 4);
                    add4(a0, ldh4(h1, (size_t)e0.x * 16 + f4));
                    add4(a1, ldh4(h1, (size_t)e0.y * 16 + f4));
                    add4(a2, ldh4(h1, (size_t)e0.z * 16 + f4));
                    add4(a3, ldh4(h1, (size_t)e0.w * 16 + f4));
                    add4(a0, ldh4(h1, (size_t)e1.x * 16 + f4));
                    add4(a1, ldh4(h1, (size_t)e1.y * 16 + f4));
                    add4(a2, ldh4(h1, (size_t)e1.z * 16 + f4));
                    add4(a3, ldh4(h1, (size_t)e1.w * 16 + f4));
                }
                if (j + 4 <= m) {
                    ushort4 e0 = *(const ushort4*)(eidx + beg + j);
                    add4(a0, ldh4(h1, (size_t)e0.x * 16 + f4));
                    add4(a1, ldh4(h1, (size_t)e0.y * 16 + f4));
                    add4(a2, ldh4(h1, (size_t)e0.z * 16 + f4));
                    add4(a3, ldh4(h1, (size_t)e0.w * 16 + f4));
                    j += 4;
                }
                for (; j < m; ++j)
                    add4(a0, ldh4(h1, (size_t)eidx[beg + j] * 16 + f4));
                add4(a0, a1); add4(a2, a3); add4(a0, a2);
                float di = dinv[node];
                float4 self = ldh4(h1, (size_t)node * 16 + f4);
                float4 bv = ((const float4*)b1)[f4];
                float4 o;
                o.x = di * (a0.x + self.x) + bv.x;
                o.y = di * (a0.y + self.y) + bv.y;
                o.z = di * (a0.z + self.z) + bv.z;
                o.w = di * (a0.w + self.w) + bv.w;
                o.x = o.x > 0.f ? o.x : 0.f;
                o.y = o.y > 0.f ? o.y : 0.f;
                o.z = o.z > 0.f ? o.z : 0.f;
                o.w = o.w > 0.f ? o.w : 0.f;
                *(float4*)&xs[ln * 68 + f4 * 4] = o;
            }
            __syncthreads();
            if (gidx < n) {
                const int c0 = f4 * 2;
                float s0 = 0.f, s1 = 0.f;
#pragma unroll
                for (int k = 0; k < 64; ++k) {
                    float xv = xs[ln * 68 + k];
                    s0 += xv * W2s[k * 32 + c0];
                    s1 += xv * W2s[k * 32 + c0 + 1];
                }
                float d2 = dinv[n + node];          // prescale h2' = dinv2*h2raw
                ((__half2*)h2)[(size_t)node * 16 + f4] = __floats2half2_rn(s0 * d2, s1 * d2);
            }
            __syncthreads();
        }
    }
    gbar(bar, 2);

    // ---------------- Phase 4: gather2 + gemm3 ----------------
    {
        float* W3s = (float*)smem;                  // 2 KB
        float* xs  = (float*)(smem + 2048);         // 32*36 f32
        for (int i = t; i < 128; i += PT)
            ((float4*)W3s)[i] = ((const float4*)W3g)[i];
        __syncthreads();
        const int ln = t >> 3;
        const int f4 = t & 7;
        const int nu = (n + 31) / 32;
        const int* rp2 = row_ptr + n;
        const int* ct2 = cnt_g + n;
        const int* pm2 = perm + n;
        for (int u = bid; u < nu; u += GRID) {
            const int gidx = u * 32 + ln;
            const int node = (gidx < n) ? pm2[gidx] : 0;
            if (gidx < n) {
                const int beg = rp2[node];
                const int m = ct2[node];
                float4 a0 = make_float4(0.f, 0.f, 0.f, 0.f), a1 = a0, a2 = a0, a3 = a0;
                int j = 0;
                for (; j + 8 <= m; j += 8) {
                    ushort4 e0 = *(const ushort4*)(eidx + beg + j);
                    ushort4 e1 = *(const ushort4*)(eidx + beg + j + 4);
                    add4(a0, ldh4(h2, (size_t)e0.x * 8 + f4));
                    add4(a1, ldh4(h2, (size_t)e0.y * 8 + f4));
                    add4(a2, ldh4(h2, (size_t)e0.z * 8 + f4));
                    add4(a3, ldh4(h2, (size_t)e0.w * 8 + f4));
                    add4(a0, ldh4(h2, (size_t)e1.x * 8 + f4));
                    add4(a1, ldh4(h2, (size_t)e1.y * 8 + f4));
                    add4(a2, ldh4(h2, (size_t)e1.z * 8 + f4));
                    add4(a3, ldh4(h2, (size_t)e1.w * 8 + f4));
                }
                if (j + 4 <= m) {
                    ushort4 e0 = *(const ushort4*)(eidx + beg + j);
                    add4(a0, ldh4(h2, (size_t)e0.x * 8 + f4));
                    add4(a1, ldh4(h2, (size_t)e0.y * 8 + f4));
                    add4(a2, ldh4(h2, (size_t)e0.z * 8 + f4));
                    add4(a3, ldh4(h2, (size_t)e0.w * 8 + f4));
                    j += 4;
                }
                for (; j < m; ++j)
                    add4(a0, ldh4(h2, (size_t)eidx[beg + j] * 8 + f4));
                add4(a0, a1); add4(a2, a3); add4(a0, a2);
                float di = dinv[n + node];
                float4 self = ldh4(h2, (size_t)node * 8 + f4);
                float4 bv = ((const float4*)b2)[f4];
                float4 o;
                o.x = di * (a0.x + self.x) + bv.x;
                o.y = di * (a0.y + self.y) + bv.y;
                o.z = di * (a0.z + self.z) + bv.z;
                o.w = di * (a0.w + self.w) + bv.w;
                o.x = o.x > 0.f ? o.x : 0.f;
                o.y = o.y > 0.f ? o.y : 0.f;
                o.z = o.z > 0.f ? o.z : 0.f;
                o.w = o.w > 0.f ? o.w : 0.f;
                *(float4*)&xs[ln * 36 + f4 * 4] = o;
            }
            __syncthreads();
            if (gidx < n) {
                const int c0 = f4 * 2;
                float s0 = 0.f, s1 = 0.f;
#pragma unroll
                for (int k = 0; k < 32; ++k) {
                    float xv = xs[ln * 36 + k];
                    s0 += xv * W3s[k * 16 + c0];
                    s1 += xv * W3s[k * 16 + c0 + 1];
                }
                float d3 = dinv[2 * n + node];      // prescale h3' = dinv3*h3raw
                ((__half2*)h3)[(size_t)node * 8 + f4] = __floats2half2_rn(s0 * d3, s1 * d3);
            }
            __syncthreads();
        }
    }
    gbar(bar, 3);

    // ---------------- Phase 5: gather3 -> out ----------------
    {
        const int ln = t >> 2;
        const int f4 = t & 3;
        const int nu = (n + 63) / 64;
        const int* rp3 = row_ptr + 2 * n;
        const int* ct3 = cnt_g + 2 * n;
        const int* pm3 = perm + 2 * n;
        const float* dv3 = dinv + 2 * n;
        for (int u = bid; u < nu; u += GRID) {
            const int gidx = u * 64 + ln;
            if (gidx >= n) continue;
            const int node = pm3[gidx];
            const int beg = rp3[node];
            const int m = ct3[node];
            float4 a0 = make_float4(0.f, 0.f, 0.f, 0.f), a1 = a0, a2 = a0, a3 = a0;
            int j = 0;
            for (; j + 8 <= m; j += 8) {
                ushort4 e0 = *(const ushort4*)(eidx + beg + j);
                ushort4 e1 = *(const ushort4*)(eidx + beg + j + 4);
                add4(a0, ldh4(h3, (size_t)e0.x * 4 + f4));
                add4(a1, ldh4(h3, (size_t)e0.y * 4 + f4));
                add4(a2, ldh4(h3, (size_t)e0.z * 4 + f4));
                add4(a3, ldh4(h3, (size_t)e0.w * 4 + f4));
                add4(a0, ldh4(h3, (size_t)e1.x * 4 + f4));
                add4(a1, ldh4(h3, (size_t)e1.y * 4 + f4));
                add4(a2, ldh4(h3, (size_t)e1.z * 4 + f4));
                add4(a3, ldh4(h3, (size_t)e1.w * 4 + f4));
            }
            if (j + 4 <= m) {
                ushort4 e0 = *(const ushort4*)(eidx + beg + j);
                add4(a0, ldh4(h3, (size_t)e0.x * 4 + f4));
                add4(a1, ldh4(h3, (size_t)e0.y * 4 + f4));
                add4(a2, ldh4(h3, (size_t)e0.z * 4 + f4));
                add4(a3, ldh4(h3, (size_t)e0.w * 4 + f4));
                j += 4;
            }
            for (; j < m; ++j)
                add4(a0, ldh4(h3, (size_t)eidx[beg + j] * 4 + f4));
            add4(a0, a1); add4(a2, a3); add4(a0, a2);
            float di = dv3[node];
            float4 self = ldh4(h3, (size_t)node * 4 + f4);
            float4 bv = ((const float4*)b3)[f4];
            float4 o;
            o.x = di * (a0.x + self.x) + bv.x;
            o.y = di * (a0.y + self.y) + bv.y;
            o.z = di * (a0.z + self.z) + bv.z;
            o.w = di * (a0.w + self.w) + bv.w;
            o.x = o.x > 0.f ? o.x : 0.f;
            o.y = o.y > 0.f ? o.y : 0.f;
            o.z = o.z > 0.f ? o.z : 0.f;
            o.w = o.w > 0.f ? o.w : 0.f;
            ((float4*)out)[(size_t)node * 4 + f4] = o;
        }
    }
}

extern "C" void kernel_launch(void* const* d_in, const int* in_sizes, int n_in,
                              void* d_out, int out_size, void* d_ws, size_t ws_size,
                              hipStream_t stream) {
    const float* x0  = (const float*)d_in[0];
    const int*   ei1 = (const int*)d_in[1];
    const int*   ei3 = (const int*)d_in[2];
    const int*   ei9 = (const int*)d_in[3];
    const float* W1  = (const float*)d_in[4];
    const float* b1  = (const float*)d_in[5];
    const float* W2  = (const float*)d_in[6];
    const float* b2  = (const float*)d_in[7];
    const float* W3  = (const float*)d_in[8];
    const float* b3  = (const float*)d_in[9];

    const int n  = in_sizes[0] / 64;  // 50000
    const int E1 = in_sizes[1] / 2;   // 800000
    const int E3 = in_sizes[2] / 2;
    const int E9 = in_sizes[3] / 2;
    const int n3 = 3 * n;
    const int W  = (n + NB - 1) / NB; // 196

    const int nc1 = (E1 + CH - 1) / CH;
    const int nc2 = (E3 + CH - 1) / CH;
    const int nc3 = (E9 + CH - 1) / CH;
    const int nchunks = nc1 + nc2 + nc3;
    const int gemmBlks = (n + 63) / 64;

    int* gcur    = (int*)d_ws;                           // TB
    int* bar     = gcur + TB;                            // 8
    unsigned int* pairBuf = (unsigned int*)(bar + 8);    // TB*CAPE u32
    unsigned short* eidx = (unsigned short*)(pairBuf + (size_t)TB * CAPE); // TB*CAPE_E u16
    int* row_ptr = (int*)(eidx + (size_t)TB * CAPE_E);   // 3n
    int* cnt     = row_ptr + n3;                         // 3n
    float* dinv  = (float*)(cnt + n3);                   // 3n
    int* perm    = (int*)(dinv + n3);                    // 3n
    __half* h1   = (__half*)(perm + n3);                 // n*64 fp16
    __half* h2   = h1 + (size_t)n * 64;                  // n*32 fp16
    __half* h3   = h2 + (size_t)n * 32;                  // n*16 fp16

    hipMemsetAsync(gcur, 0, (TB + 8) * sizeof(int), stream);
    mega<<<GRID, PT, 0, stream>>>(
        ei1, ei1 + E1, E1, ei3, ei3 + E3, E3, ei9, ei9 + E9, E9,
        nc1, nc2, W, nchunks, gemmBlks, n,
        gcur, bar, pairBuf, eidx, row_ptr, cnt, dinv, perm,
        x0, W1, b1, W2, b2, W3, b3, h1, h2, h3, (float*)d_out);
}

// Round 6
// 156.732 us; speedup vs baseline: 3.9214x; 3.9214x over previous
//
#include <hip/hip_runtime.h>
#include <hip/hip_fp16.h>

// ---------------------------------------------------------------------------
// 3-layer GCN, 5 dispatches (R18 = revert to R16; R17 mega-kernel refuted):
//  K1: [phase1 bucket-sort (counting sort, LDS-staged -> coalesced writes)]
//      ∥ [raw gemm1 h1 = x0 @ W1]
//  K2: phase2 per-bucket node sort -> row_ptr/cnt/dinv + u16 eidx (768 wgs);
//      layer-0 blocks prescale h1 in place (h1' = dinv1*h1raw); counting-sort
//      nodes by degree -> perm
//  K3: gather1 (plain adds over prescaled h1', nodes via perm) + gemm2
//  K4: gather2 (plain adds over prescaled h2', nodes via perm) + gemm3
//  K5: gather3 (plain adds over prescaled h3', nodes via perm) -> out
// h* fp16 (fp32 accumulate). Prescaled h1'/h2'/h3' remove per-edge dinv
// broadcasts (R14, -5us).
// NOTE (R6): f32 LDS atomicAdd is a serializing slow path on gfx950.
// NOTE (R12): hipLaunchCooperativeKernel fails silently under graph capture.
// NOTE (R13): phase1 LDS-staged scatter -> coalesced arena writes. -9us.
// NOTE (R15/R16): degree-sort perm / barrier reduction: flat -> kernels are
//   not issue- or barrier-bound.
// NOTE (R17, REFUTED): single persistent kernel w/ manual grid barriers =
//   614us (3.8x WORSE). Occupancy 36%, HBM 1-4% peak: the gathers are
//   MEMORY-LATENCY-BOUND and need full per-phase TLP (work-sized grids,
//   up to 48 waves/CU); co-residency caps at 12 waves/CU. Keep the
//   multi-dispatch structure permanently.
// ---------------------------------------------------------------------------

#define NB   256            // buckets per layer (W = ceil(n/NB) = 196 < 512)
#define NL   3
#define TB   (NB * NL)      // 768 buckets
#define CAPE 6400           // arena capacity per bucket (mean fill ~3125)
#define CAPE_E (CAPE + 8)   // u16 eidx arena stride (+8 spill room)
#define CH   4096           // edges per phase-1 chunk
#define P1T  256
#define EPT  (CH / P1T)     // 16
#define P2T  512

__device__ __forceinline__ void decode_chunk(int g, int nc1, int nc2,
                                             const int* s1, const int* d1, int E1,
                                             const int* s2, const int* d2, int E2,
                                             const int* s3, const int* d3, int E3,
                                             const int** src, const int** dst, int* E, int* l,
                                             int* gout) {
    if (g < nc1)            { *src = s1; *dst = d1; *E = E1; *l = 0; }
    else if (g < nc1 + nc2) { *src = s2; *dst = d2; *E = E2; *l = 1; g -= nc1; }
    else                    { *src = s3; *dst = d3; *E = E3; *l = 2; g -= nc1 + nc2; }
    *gout = g;
}

__device__ __forceinline__ void fma4(float4& a, float s, const float4& w) {
    a.x += s * w.x; a.y += s * w.y; a.z += s * w.z; a.w += s * w.w;
}
__device__ __forceinline__ void add4(float4& a, const float4& v) {
    a.x += v.x; a.y += v.y; a.z += v.z; a.w += v.w;
}
__device__ __forceinline__ float4 ldh4(const __half* h, size_t idx4) {
    uint2 r = ((const uint2*)h)[idx4];
    __half2 a = *reinterpret_cast<__half2*>(&r.x);
    __half2 b = *reinterpret_cast<__half2*>(&r.y);
    float2 fa = __half22float2(a), fb = __half22float2(b);
    return make_float4(fa.x, fa.y, fb.x, fb.y);
}
__device__ __forceinline__ void sth4(__half* h, size_t idx4, float4 v) {
    __half2 a = __floats2half2_rn(v.x, v.y);
    __half2 b = __floats2half2_rn(v.z, v.w);
    uint2 r;
    r.x = *reinterpret_cast<unsigned*>(&a);
    r.y = *reinterpret_cast<unsigned*>(&b);
    ((uint2*)h)[idx4] = r;
}

// Inclusive wave scan (wave64) of v; returns inclusive prefix for this lane.
__device__ __forceinline__ int wave_incl_scan(int v) {
    int incl = v;
#pragma unroll
    for (int off = 1; off < 64; off <<= 1) {
        int u = __shfl_up(incl, (unsigned)off, 64);
        if ((threadIdx.x & 63) >= off) incl += u;
    }
    return incl;
}

// K1: blocks [0,nchunks) = phase1 counting sort; blocks [nchunks,...) = gemm1.
__global__ void __launch_bounds__(P1T) k1_phase1_gemm1(
        const int* __restrict__ s1, const int* __restrict__ d1, int E1,
        const int* __restrict__ s2, const int* __restrict__ d2, int E2,
        const int* __restrict__ s3, const int* __restrict__ d3, int E3,
        int nc1, int nc2, int W, int nchunks,
        int* __restrict__ gcur, unsigned int* __restrict__ pairBuf,
        const float* __restrict__ x0, const float* __restrict__ W1g,
        __half* __restrict__ h1) {
    __shared__ __align__(16) char smem[24576];
    __shared__ int wsum[4];
    const int t = threadIdx.x;
    if (blockIdx.x < (unsigned)nchunks) {
        int* hist = (int*)smem;                       // 256
        int* eofs = hist + NB;                        // 256 excl LDS offsets
        int* bo   = eofs + NB;                        // 256 global write base
        int* lcur = bo + NB;                          // 256 LDS cursors
        unsigned* stage = (unsigned*)(smem + 4096);   // 16KB bucket-major pairs
        unsigned char* stageQ = (unsigned char*)(smem + 20480); // 4KB tags
        hist[t] = 0;
        __syncthreads();
        const int* src; const int* dst; int E, l, g;
        decode_chunk(blockIdx.x, nc1, nc2, s1, d1, E1, s2, d2, E2, s3, d3, E3,
                     &src, &dst, &E, &l, &g);
        const int e0 = g * CH;
        const int lbase = l * NB;
        unsigned pv[EPT];
        int bn[EPT];                    // local bucket q in [0,NB) or -1
        if (E - e0 >= CH) {
            const int4* s4 = (const int4*)(src + e0);
            const int4* d4 = (const int4*)(dst + e0);
#pragma unroll
            for (int w = 0; w < EPT / 4; ++w) {
                int4 sv = s4[t + w * P1T];
                int4 dv = d4[t + w * P1T];
                int q, i = w * 4;
                q = dv.x / W; bn[i+0] = q; pv[i+0] = ((unsigned)sv.x << 9) | (unsigned)(dv.x - q * W);
                q = dv.y / W; bn[i+1] = q; pv[i+1] = ((unsigned)sv.y << 9) | (unsigned)(dv.y - q * W);
                q = dv.z / W; bn[i+2] = q; pv[i+2] = ((unsigned)sv.z << 9) | (unsigned)(dv.z - q * W);
                q = dv.w / W; bn[i+3] = q; pv[i+3] = ((unsigned)sv.w << 9) | (unsigned)(dv.w - q * W);
            }
        } else {
#pragma unroll
            for (int i = 0; i < EPT; ++i) {
                int e = e0 + t + i * P1T;
                if (e < E) {
                    int s = src[e], d = dst[e];
                    int q = d / W;
                    bn[i] = q;
                    pv[i] = ((unsigned)s << 9) | (unsigned)(d - q * W);
                } else bn[i] = -1;
            }
        }
#pragma unroll
        for (int i = 0; i < EPT; ++i)
            if (bn[i] >= 0) atomicAdd(&hist[bn[i]], 1);
        __syncthreads();
        // Wave-shuffle exclusive scan over NB=256 counts (4 waves).
        const int c = hist[t];
        int incl = wave_incl_scan(c);
        const int lane = t & 63, wid = t >> 6;
        if (lane == 63) wsum[wid] = incl;
        __syncthreads();
        int base = 0, total = 0;
#pragma unroll
        for (int w = 0; w < 4; ++w) {
            int s = wsum[w];
            total += s;
            if (w < wid) base += s;
        }
        const int excl = base + incl - c;
        eofs[t] = excl;
        lcur[t] = excl;
        bo[t] = (lbase + t) * CAPE + (c ? atomicAdd(&gcur[lbase + t], c) : 0);
        __syncthreads();
        // LDS scatter: bucket-major staging.
#pragma unroll
        for (int i = 0; i < EPT; ++i) {
            if (bn[i] >= 0) {
                int r = atomicAdd(&lcur[bn[i]], 1);
                stage[r] = pv[i];
                stageQ[r] = (unsigned char)bn[i];
            }
        }
        __syncthreads();
        // Coalesced writeout: consecutive i -> consecutive global slots per run.
        for (int i = t; i < total; i += P1T) {
            int q = stageQ[i];
            int k = bo[q] + (i - eofs[q]);
            if (k < (lbase + q + 1) * CAPE) pairBuf[k] = stage[i];
        }
    } else {
        float* Ws = (float*)smem;               // 16 KB
        const int bid = blockIdx.x - nchunks;
        for (int i = t; i < 1024; i += P1T)
            ((float4*)Ws)[i] = ((const float4*)W1g)[i];
        __syncthreads();
        const int tc = t % 16;
        const int tr = t / 16;                  // 0..15 -> 64 rows/block
        const int row0 = bid * 64 + tr * 4;
        const float4* x4 = (const float4*)x0;
        const float4* Ws4 = (const float4*)Ws;
        float4 acc[4];
#pragma unroll
        for (int r = 0; r < 4; ++r) acc[r] = make_float4(0.f, 0.f, 0.f, 0.f);
        int rowc[4];
#pragma unroll
        for (int r = 0; r < 4; ++r) rowc[r] = min(row0 + r, 49999);
        for (int k0 = 0; k0 < 64; k0 += 4) {
            float4 wv0 = Ws4[(k0 + 0) * 16 + tc];
            float4 wv1 = Ws4[(k0 + 1) * 16 + tc];
            float4 wv2 = Ws4[(k0 + 2) * 16 + tc];
            float4 wv3 = Ws4[(k0 + 3) * 16 + tc];
#pragma unroll
            for (int r = 0; r < 4; ++r) {
                float4 xv = x4[(size_t)rowc[r] * 16 + (k0 / 4)];
                fma4(acc[r], xv.x, wv0);
                fma4(acc[r], xv.y, wv1);
                fma4(acc[r], xv.z, wv2);
                fma4(acc[r], xv.w, wv3);
            }
        }
#pragma unroll
        for (int r = 0; r < 4; ++r) {
            int row = row0 + r;
            if (row < 50000) sth4(h1, (size_t)row * 16 + tc, acc[r]);
        }
    }
}

// K2: phase2 per-bucket node sort (u16 eidx) + layer-0 h1 prescale +
// counting-sort nodes by degree -> perm.
__global__ void __launch_bounds__(P2T) k2_phase2(
        const unsigned int* __restrict__ pairBuf, const int* __restrict__ gcur,
        int n, int W,
        int* __restrict__ row_ptr, int* __restrict__ cnt_g,
        float* __restrict__ dinv, unsigned short* __restrict__ eidx,
        __half* __restrict__ h1, int* __restrict__ perm) {
    __shared__ __align__(16) char smem[19456];
    __shared__ int wsum[8];
    int* lcnt  = (int*)smem;                               // 2KB (also kcnt)
    int* lscan = lcnt + P2T;                               // 2KB (also kofs)
    unsigned short* stage = (unsigned short*)(lscan + P2T);// 13312B
    float* dloc = (float*)(smem + 17408);                  // 2KB
    const int bid = blockIdx.x;
    const int l = bid / NB, k = bid % NB;
    const int lo = k * W;
    const int hi = min(n, lo + W);
    const int Wn = hi - lo;
    const int segE = min(gcur[bid], CAPE);
    const size_t base  = (size_t)bid * CAPE;
    const int    baseE = bid * CAPE_E;
    const int t = threadIdx.x;
    const int lane = t & 63, wid = t >> 6;
    lcnt[t] = 0;
    __syncthreads();
    for (int i = t; i < segE; i += P2T)
        atomicAdd(&lcnt[pairBuf[base + i] & 511u], 1);
    __syncthreads();
    const int v = lcnt[t];
    const int vp = (v + 3) & ~3;
    // Wave-shuffle exclusive scan over 512 padded counts (8 waves).
    int incl = wave_incl_scan(vp);
    if (lane == 63) wsum[wid] = incl;
    __syncthreads();
    int sbase = 0, segEp = 0;
#pragma unroll
    for (int w = 0; w < 8; ++w) {
        int s = wsum[w];
        segEp += s;
        if (w < wid) sbase += s;
    }
    const int pexcl = sbase + incl - vp;
    if (t < Wn) {
        int node = l * n + lo + t;
        row_ptr[node] = baseE + pexcl;
        cnt_g[node] = v;
        float dv = rsqrtf((float)v + 1.0f);   // +1 self-loop
        dinv[node] = dv;
        dloc[t] = dv;
    }
    __syncthreads();
    lcnt[t] = pexcl;
    __syncthreads();
    const bool lds_ok = (segEp <= CAPE);
    for (int i = t; i < segE; i += P2T) {
        unsigned p = pairBuf[base + i];
        int pos = atomicAdd(&lcnt[p & 511u], 1);
        unsigned short s = (unsigned short)(p >> 9);
        if (lds_ok) stage[pos] = s;
        else if (pos < CAPE_E) eidx[baseE + pos] = s;
    }
    __syncthreads();
    if (lds_ok) {
        const int4* st4 = (const int4*)stage;
        int4* e4 = (int4*)(eidx + baseE);
        int m16 = (segEp + 7) >> 3;
        for (int i = t; i < m16; i += P2T) e4[i] = st4[i];
    }
    // Layer-0 blocks prescale their h1 rows in place: h1' = dinv1 * h1raw.
    if (l == 0) {
        for (int i = t; i < Wn * 16; i += P2T) {
            int r = i >> 4, cc = i & 15;
            size_t idx = (size_t)(lo + r) * 16 + cc;
            float4 vv = ldh4(h1, idx);
            float s = dloc[r];
            vv.x *= s; vv.y *= s; vv.z *= s; vv.w *= s;
            sth4(h1, idx, vv);
        }
    }
    // Counting-sort nodes by degree -> perm (replaces R15 bitonic).
    __syncthreads();               // scatter-cursor use of lcnt done
    lcnt[t] = 0;                   // reuse lcnt as degree histogram (512 bins)
    __syncthreads();
    int key = 0, myr = 0;
    if (t < Wn) {
        key = min(v, 511);
        myr = atomicAdd(&lcnt[key], 1);
    }
    __syncthreads();
    const int c2 = lcnt[t];
    int incl2 = wave_incl_scan(c2);
    if (lane == 63) wsum[wid] = incl2;
    __syncthreads();
    int base2 = 0;
#pragma unroll
    for (int w = 0; w < 8; ++w) {
        int s = wsum[w];
        if (w < wid) base2 += s;
    }
    lscan[t] = base2 + incl2 - c2;  // exclusive bin offset
    __syncthreads();
    if (t < Wn) perm[l * n + lo + lscan[key] + myr] = lo + t;
}

// K3: gather1 (plain adds over prescaled h1', nodes via perm) + fused gemm2.
// 256 thr = 16 nodes x 16 lanes.
__global__ void __launch_bounds__(256) k3_gather1_gemm2(
        const int* __restrict__ row_ptr, const int* __restrict__ cnt,
        const unsigned short* __restrict__ eidx, const float* __restrict__ dinv1,
        const float* __restrict__ dinv2, const int* __restrict__ perm,
        const __half* __restrict__ h1, const float* __restrict__ b1,
        const float* __restrict__ W2g, __half* __restrict__ h2, int n) {
    __shared__ float xs[16 * 68];
    __shared__ float W2s[64 * 32];
    for (int i = threadIdx.x; i < 512; i += 256)
        ((float4*)W2s)[i] = ((const float4*)W2g)[i];
    const int ln = threadIdx.x >> 4;
    const int f4 = threadIdx.x & 15;
    const int gidx = blockIdx.x * 16 + ln;
    const int node = (gidx < n) ? perm[gidx] : 0;
    if (gidx < n) {
        const int beg = row_ptr[node];
        const int m = cnt[node];
        float4 a0 = make_float4(0.f, 0.f, 0.f, 0.f), a1 = a0, a2 = a0, a3 = a0;
        int j = 0;
        for (; j + 8 <= m; j += 8) {
            ushort4 e0 = *(const ushort4*)(eidx + beg + j);
            ushort4 e1 = *(const ushort4*)(eidx + beg + j + 4);
            add4(a0, ldh4(h1, (size_t)e0.x * 16 + f4));
            add4(a1, ldh4(h1, (size_t)e0.y * 16 + f4));
            add4(a2, ldh4(h1, (size_t)e0.z * 16 + f4));
            add4(a3, ldh4(h1, (size_t)e0.w * 16 + f4));
            add4(a0, ldh4(h1, (size_t)e1.x * 16 + f4));
            add4(a1, ldh4(h1, (size_t)e1.y * 16 + f4));
            add4(a2, ldh4(h1, (size_t)e1.z * 16 + f4));
            add4(a3, ldh4(h1, (size_t)e1.w * 16 + f4));
        }
        if (j + 4 <= m) {
            ushort4 e0 = *(const ushort4*)(eidx + beg + j);
            add4(a0, ldh4(h1, (size_t)e0.x * 16 + f4));
            add4(a1, ldh4(h1, (size_t)e0.y * 16 + f4));
            add4(a2, ldh4(h1, (size_t)e0.z * 16 + f4));
            add4(a3, ldh4(h1, (size_t)e0.w * 16 + f4));
            j += 4;
        }
        for (; j < m; ++j)
            add4(a0, ldh4(h1, (size_t)eidx[beg + j] * 16 + f4));
        add4(a0, a1); add4(a2, a3); add4(a0, a2);
        float di = dinv1[node];
        float4 self = ldh4(h1, (size_t)node * 16 + f4);  // already dinv1*h1raw
        float4 bv = ((const float4*)b1)[f4];
        float4 o;
        o.x = di * (a0.x + self.x) + bv.x;
        o.y = di * (a0.y + self.y) + bv.y;
        o.z = di * (a0.z + self.z) + bv.z;
        o.w = di * (a0.w + self.w) + bv.w;
        o.x = o.x > 0.f ? o.x : 0.f;
        o.y = o.y > 0.f ? o.y : 0.f;
        o.z = o.z > 0.f ? o.z : 0.f;
        o.w = o.w > 0.f ? o.w : 0.f;
        *(float4*)&xs[ln * 68 + f4 * 4] = o;   // x1 row, LDS only (fp32)
    }
    __syncthreads();
    if (gidx < n) {
        const int c0 = f4 * 2;
        float s0 = 0.f, s1 = 0.f;
#pragma unroll
        for (int k = 0; k < 64; ++k) {
            float xv = xs[ln * 68 + k];
            s0 += xv * W2s[k * 32 + c0];
            s1 += xv * W2s[k * 32 + c0 + 1];
        }
        float d2 = dinv2[node];                 // prescale: h2' = dinv2 * h2raw
        ((__half2*)h2)[(size_t)node * 16 + f4] = __floats2half2_rn(s0 * d2, s1 * d2);
    }
}

// K4: gather2 (plain adds over prescaled h2', nodes via perm) + fused gemm3.
// 256 thr = 32 nodes x 8 lanes.
__global__ void __launch_bounds__(256) k4_gather2_gemm3(
        const int* __restrict__ row_ptr2, const int* __restrict__ cnt2,
        const unsigned short* __restrict__ eidx, const float* __restrict__ dinv2,
        const float* __restrict__ dinv3, const int* __restrict__ perm,
        const __half* __restrict__ h2, const float* __restrict__ b2,
        const float* __restrict__ W3g, __half* __restrict__ h3, int n) {
    __shared__ float xs[32 * 36];
    __shared__ float W3s[32 * 16];
    for (int i = threadIdx.x; i < 128; i += 256)
        ((float4*)W3s)[i] = ((const float4*)W3g)[i];
    const int ln = threadIdx.x >> 3;
    const int f4 = threadIdx.x & 7;
    const int gidx = blockIdx.x * 32 + ln;
    const int node = (gidx < n) ? perm[gidx] : 0;
    if (gidx < n) {
        const int beg = row_ptr2[node];
        const int m = cnt2[node];
        float4 a0 = make_float4(0.f, 0.f, 0.f, 0.f), a1 = a0, a2 = a0, a3 = a0;
        int j = 0;
        for (; j + 8 <= m; j += 8) {
            ushort4 e0 = *(const ushort4*)(eidx + beg + j);
            ushort4 e1 = *(const ushort4*)(eidx + beg + j + 4);
            add4(a0, ldh4(h2, (size_t)e0.x * 8 + f4));
            add4(a1, ldh4(h2, (size_t)e0.y * 8 + f4));
            add4(a2, ldh4(h2, (size_t)e0.z * 8 + f4));
            add4(a3, ldh4(h2, (size_t)e0.w * 8 + f4));
            add4(a0, ldh4(h2, (size_t)e1.x * 8 + f4));
            add4(a1, ldh4(h2, (size_t)e1.y * 8 + f4));
            add4(a2, ldh4(h2, (size_t)e1.z * 8 + f4));
            add4(a3, ldh4(h2, (size_t)e1.w * 8 + f4));
        }
        if (j + 4 <= m) {
            ushort4 e0 = *(const ushort4*)(eidx + beg + j);
            add4(a0, ldh4(h2, (size_t)e0.x * 8 + f4));
            add4(a1, ldh4(h2, (size_t)e0.y * 8 + f4));
            add4(a2, ldh4(h2, (size_t)e0.z * 8 + f4));
            add4(a3, ldh4(h2, (size_t)e0.w * 8 + f4));
            j += 4;
        }
        for (; j < m; ++j)
            add4(a0, ldh4(h2, (size_t)eidx[beg + j] * 8 + f4));
        add4(a0, a1); add4(a2, a3); add4(a0, a2);
        float di = dinv2[node];
        float4 self = ldh4(h2, (size_t)node * 8 + f4);  // already dinv2*h2raw
        float4 bv = ((const float4*)b2)[f4];
        float4 o;
        o.x = di * (a0.x + self.x) + bv.x;
        o.y = di * (a0.y + self.y) + bv.y;
        o.z = di * (a0.z + self.z) + bv.z;
        o.w = di * (a0.w + self.w) + bv.w;
        o.x = o.x > 0.f ? o.x : 0.f;
        o.y = o.y > 0.f ? o.y : 0.f;
        o.z = o.z > 0.f ? o.z : 0.f;
        o.w = o.w > 0.f ? o.w : 0.f;
        *(float4*)&xs[ln * 36 + f4 * 4] = o;   // x2 row, LDS only (fp32)
    }
    __syncthreads();
    if (gidx < n) {
        const int c0 = f4 * 2;
        float s0 = 0.f, s1 = 0.f;
#pragma unroll
        for (int k = 0; k < 32; ++k) {
            float xv = xs[ln * 36 + k];
            s0 += xv * W3s[k * 16 + c0];
            s1 += xv * W3s[k * 16 + c0 + 1];
        }
        float d3 = dinv3[node];                 // prescale: h3' = dinv3 * h3raw
        ((__half2*)h3)[(size_t)node * 8 + f4] = __floats2half2_rn(s0 * d3, s1 * d3);
    }
}

// K5: gather3 (plain adds over prescaled h3', nodes via perm) -> fp32 out.
// 64 nodes x 4 lanes.
__global__ void __launch_bounds__(256) k5_gather3(
        const int* __restrict__ row_ptr3, const int* __restrict__ cnt3,
        const unsigned short* __restrict__ eidx, const float* __restrict__ dinv3,
        const int* __restrict__ perm,
        const __half* __restrict__ h3, const float* __restrict__ b3,
        float* __restrict__ out, int n) {
    const int ln = threadIdx.x >> 2;
    const int f4 = threadIdx.x & 3;
    const int gidx = blockIdx.x * 64 + ln;
    if (gidx >= n) return;
    const int node = perm[gidx];
    const int beg = row_ptr3[node];
    const int m = cnt3[node];
    float4 a0 = make_float4(0.f, 0.f, 0.f, 0.f), a1 = a0, a2 = a0, a3 = a0;
    int j = 0;
    for (; j + 8 <= m; j += 8) {
        ushort4 e0 = *(const ushort4*)(eidx + beg + j);
        ushort4 e1 = *(const ushort4*)(eidx + beg + j + 4);
        add4(a0, ldh4(h3, (size_t)e0.x * 4 + f4));
        add4(a1, ldh4(h3, (size_t)e0.y * 4 + f4));
        add4(a2, ldh4(h3, (size_t)e0.z * 4 + f4));
        add4(a3, ldh4(h3, (size_t)e0.w * 4 + f4));
        add4(a0, ldh4(h3, (size_t)e1.x * 4 + f4));
        add4(a1, ldh4(h3, (size_t)e1.y * 4 + f4));
        add4(a2, ldh4(h3, (size_t)e1.z * 4 + f4));
        add4(a3, ldh4(h3, (size_t)e1.w * 4 + f4));
    }
    if (j + 4 <= m) {
        ushort4 e0 = *(const ushort4*)(eidx + beg + j);
        add4(a0, ldh4(h3, (size_t)e0.x * 4 + f4));
        add4(a1, ldh4(h3, (size_t)e0.y * 4 + f4));
        add4(a2, ldh4(h3, (size_t)e0.z * 4 + f4));
        add4(a3, ldh4(h3, (size_t)e0.w * 4 + f4));
        j += 4;
    }
    for (; j < m; ++j)
        add4(a0, ldh4(h3, (size_t)eidx[beg + j] * 4 + f4));
    add4(a0, a1); add4(a2, a3); add4(a0, a2);
    float di = dinv3[node];
    float4 self = ldh4(h3, (size_t)node * 4 + f4);  // already dinv3*h3raw
    float4 bv = ((const float4*)b3)[f4];
    float4 o;
    o.x = di * (a0.x + self.x) + bv.x;
    o.y = di * (a0.y + self.y) + bv.y;
    o.z = di * (a0.z + self.z) + bv.z;
    o.w = di * (a0.w + self.w) + bv.w;
    o.x = o.x > 0.f ? o.x : 0.f;
    o.y = o.y > 0.f ? o.y : 0.f;
    o.z = o.z > 0.f ? o.z : 0.f;
    o.w = o.w > 0.f ? o.w : 0.f;
    ((float4*)out)[(size_t)node * 4 + f4] = o;
}

extern "C" void kernel_launch(void* const* d_in, const int* in_sizes, int n_in,
                              void* d_out, int out_size, void* d_ws, size_t ws_size,
                              hipStream_t stream) {
    const float* x0  = (const float*)d_in[0];
    const int*   ei1 = (const int*)d_in[1];
    const int*   ei3 = (const int*)d_in[2];
    const int*   ei9 = (const int*)d_in[3];
    const float* W1  = (const float*)d_in[4];
    const float* b1  = (const float*)d_in[5];
    const float* W2  = (const float*)d_in[6];
    const float* b2  = (const float*)d_in[7];
    const float* W3  = (const float*)d_in[8];
    const float* b3  = (const float*)d_in[9];

    const int n  = in_sizes[0] / 64;  // 50000
    const int E1 = in_sizes[1] / 2;   // 800000
    const int E3 = in_sizes[2] / 2;
    const int E9 = in_sizes[3] / 2;
    const int n3 = 3 * n;
    const int W  = (n + NB - 1) / NB; // 196

    const int nc1 = (E1 + CH - 1) / CH;
    const int nc2 = (E3 + CH - 1) / CH;
    const int nc3 = (E9 + CH - 1) / CH;
    const int nchunks = nc1 + nc2 + nc3;
    const int gemmBlks = (n + 63) / 64;

    int* gcur    = (int*)d_ws;                           // TB
    unsigned int* pairBuf = (unsigned int*)(gcur + TB);  // TB*CAPE u32
    unsigned short* eidx = (unsigned short*)(pairBuf + (size_t)TB * CAPE); // TB*CAPE_E u16
    int* row_ptr = (int*)(eidx + (size_t)TB * CAPE_E);   // 3n
    int* cnt     = row_ptr + n3;                         // 3n
    float* dinv  = (float*)(cnt + n3);                   // 3n
    int* perm    = (int*)(dinv + n3);                    // 3n
    __half* h1   = (__half*)(perm + n3);                 // n*64 fp16
    __half* h2   = h1 + (size_t)n * 64;                  // n*32 fp16
    __half* h3   = h2 + (size_t)n * 32;                  // n*16 fp16

    hipMemsetAsync(gcur, 0, TB * sizeof(int), stream);
    k1_phase1_gemm1<<<nchunks + gemmBlks, P1T, 0, stream>>>(
        ei1, ei1 + E1, E1, ei3, ei3 + E3, E3, ei9, ei9 + E9, E9,
        nc1, nc2, W, nchunks, gcur, pairBuf, x0, W1, h1);
    k2_phase2<<<TB, P2T, 0, stream>>>(
        pairBuf, gcur, n, W, row_ptr, cnt, dinv, eidx, h1, perm);
    k3_gather1_gemm2<<<(n + 15) / 16, 256, 0, stream>>>(
        row_ptr, cnt, eidx, dinv, dinv + n, perm, h1, b1, W2, h2, n);
    k4_gather2_gemm3<<<(n + 31) / 32, 256, 0, stream>>>(
        row_ptr + n, cnt + n, eidx, dinv + n, dinv + 2 * n, perm + n, h2, b2, W3, h3, n);
    k5_gather3<<<(n + 63) / 64, 256, 0, stream>>>(
        row_ptr + 2 * n, cnt + 2 * n, eidx, dinv + 2 * n, perm + 2 * n, h3, b3, (float*)d_out, n);
}